// Round 1
// baseline (685.241 us; speedup 1.0000x reference)
//
#include <hip/hip_runtime.h>
#include <math.h>

// GaussianSampleST fused kernel (fp32, no workspace needed)
// x:(16,64,30,64,44)  out:(16,64,30,48,22)
// Block = (n, t_out, channel-group-of-8); grid = 16*30*8 = 3840, 256 threads.

#define EPS_ 1e-8f

__global__ __launch_bounds__(256) void gst_kernel(
    const float* __restrict__ x,
    const float* __restrict__ dx,  const float* __restrict__ dy,
    const float* __restrict__ ls2, const float* __restrict__ ld,
    const float* __restrict__ lg,
    const float* __restrict__ dtp, const float* __restrict__ ldt,
    const float* __restrict__ lgt,
    float* __restrict__ out)
{
    __shared__ float FyT[64][36];     // [h][i]  (Fy row-normalized, pre-scaled by Ws*gamma)
    __shared__ float FxT[44][24];     // [w][j]  (Fx row-normalized)
    __shared__ float t2s[8][64][24];  // [c][h][j] staging (j 22,23 zeroed)

    const int tid = threadIdx.x;
    int b = blockIdx.x;
    const int cg = b & 7; b >>= 3;
    const int tq = b % 30;
    const int n  = b / 30;

    // ---- temporal interpolation params (block-uniform) ----
    const float dtv     = tanhf(dtp[n]) * 15.f + 15.f;
    const float delta_t = expf(ldt[n]);
    const float gamma_t = 1.f / (1.f + expf(-lgt[n]));
    float mu_t = dtv + ((float)tq - 15.f) * delta_t;
    mu_t = mu_t / 29.f * 2.f - 1.f;
    const float iy  = ((mu_t + 1.f) * 30.f - 1.f) * 0.5f;
    const float iy0 = floorf(iy);
    const float w1  = iy - iy0;
    const int   i0  = (int)iy0;
    const int   i1  = i0 + 1;
    const float W0 = (i0 >= 0 && i0 < 30) ? 0.5f * gamma_t * (1.f - w1) : 0.f;
    const float W1 = (i1 >= 0 && i1 < 30) ? 0.5f * gamma_t * w1 : 0.f;
    const int t0 = min(max(i0, 0), 29);
    const int t1 = min(max(i1, 0), 29);

    // thread mappings
    const int c_loc = tid >> 5;        // 0..7   (both GEMMs)
    const int hp    = tid & 31;        // GEMM1: rows 2*hp, 2*hp+1
    const int jt    = tid & 3;         // GEMM2: j-tile base 6*jt
    const int it    = (tid >> 2) & 7;  // GEMM2: i-tile base 4*it
    const int j0    = 6 * jt;
    const int i0r   = 4 * it;

    float acc2[4][6];
#pragma unroll
    for (int r = 0; r < 4; ++r)
#pragma unroll
        for (int s2 = 0; s2 < 6; ++s2) acc2[r][s2] = 0.f;

#pragma unroll 1
    for (int s = 0; s < 2; ++s) {
        const float Ws = s ? W1 : W0;
        const int   ts = s ? t1 : t0;
        if (Ws == 0.f) continue;          // block-uniform branch

        __syncthreads();  // protect LDS reuse from previous source

        // ---- per-source attention params into LDS ----
        {
            const int nt = n * 30 + ts;
            const float sigma2 = expf(ls2[nt]);
            const float inv2s2 = 0.5f / sigma2;
            const float delta  = expf(ld[nt]);
            const float gamma  = 1.f / (1.f + expf(-lg[nt]));
            const float A      = Ws * gamma;
            if (tid < 32) {
                // Fy row i = tid over h=0..63, fold A into normalization
                float pod = dy[nt] + 0.5f * (ts >= 1 ? dy[nt - 1] : 0.f)
                                   + 0.5f * (ts >= 2 ? dy[nt - 2] : 0.f);
                const float muy = tanhf(pod) * 32.f + 32.f;
                const float mu  = muy + ((float)tid - 16.f) * delta;
                float sum = 0.f;
                for (int h = 0; h < 64; ++h) {
                    float d = (float)h - mu; sum += expf(-d * d * inv2s2);
                }
                const float sc = A / fmaxf(sum, EPS_);
                for (int h = 0; h < 64; ++h) {
                    float d = (float)h - mu;
                    FyT[h][tid] = expf(-d * d * inv2s2) * sc;
                }
            } else if (tid < 54) {
                // Fx row j over w=0..43
                const int j = tid - 32;
                float pod = dx[nt] + 0.5f * (ts >= 1 ? dx[nt - 1] : 0.f)
                                   + 0.5f * (ts >= 2 ? dx[nt - 2] : 0.f);
                const float mux = tanhf(pod) * 22.f + 22.f;
                const float mu  = mux + ((float)j - 11.f) * delta;
                float sum = 0.f;
                for (int w = 0; w < 44; ++w) {
                    float d = (float)w - mu; sum += expf(-d * d * inv2s2);
                }
                const float sc = 1.f / fmaxf(sum, EPS_);
                for (int w = 0; w < 44; ++w) {
                    float d = (float)w - mu;
                    FxT[w][j] = expf(-d * d * inv2s2) * sc;
                }
            }
        }
        __syncthreads();

        // ---- GEMM1: t2s[c][h][j] = sum_w X[c][h][w] * FxT[w][j] ----
        {
            float a0[22], a1[22];
#pragma unroll
            for (int j = 0; j < 22; ++j) { a0[j] = 0.f; a1[j] = 0.f; }

            const size_t xoff =
                ((((size_t)n * 64 + (size_t)(cg * 8 + c_loc)) * 30 + (size_t)ts) * 64
                 + (size_t)(2 * hp)) * 44;
            const float4* xr0 = reinterpret_cast<const float4*>(x + xoff);
            const float4* xr1 = reinterpret_cast<const float4*>(x + xoff + 44);

#pragma unroll 2
            for (int wi = 0; wi < 11; ++wi) {
                const float4 xa = xr0[wi];
                const float4 xb = xr1[wi];
                const float xav[4] = { xa.x, xa.y, xa.z, xa.w };
                const float xbv[4] = { xb.x, xb.y, xb.z, xb.w };
#pragma unroll
                for (int k = 0; k < 4; ++k) {
                    const float4* fxr =
                        reinterpret_cast<const float4*>(&FxT[4 * wi + k][0]);
                    const float4 f0 = fxr[0], f1 = fxr[1], f2 = fxr[2],
                                 f3 = fxr[3], f4 = fxr[4];
                    const float2 f5 =
                        *reinterpret_cast<const float2*>(&FxT[4 * wi + k][20]);
                    const float fv[22] = { f0.x, f0.y, f0.z, f0.w,
                                           f1.x, f1.y, f1.z, f1.w,
                                           f2.x, f2.y, f2.z, f2.w,
                                           f3.x, f3.y, f3.z, f3.w,
                                           f4.x, f4.y, f4.z, f4.w,
                                           f5.x, f5.y };
                    const float va = xav[k], vb = xbv[k];
#pragma unroll
                    for (int j = 0; j < 22; ++j) {
                        a0[j] += va * fv[j];
                        a1[j] += vb * fv[j];
                    }
                }
            }
            // store (j 22,23 zeroed so GEMM2 can read padded rows safely)
            float4* d0 = reinterpret_cast<float4*>(&t2s[c_loc][2 * hp][0]);
            float4* d1 = reinterpret_cast<float4*>(&t2s[c_loc][2 * hp + 1][0]);
            d0[0] = make_float4(a0[0],  a0[1],  a0[2],  a0[3]);
            d0[1] = make_float4(a0[4],  a0[5],  a0[6],  a0[7]);
            d0[2] = make_float4(a0[8],  a0[9],  a0[10], a0[11]);
            d0[3] = make_float4(a0[12], a0[13], a0[14], a0[15]);
            d0[4] = make_float4(a0[16], a0[17], a0[18], a0[19]);
            d0[5] = make_float4(a0[20], a0[21], 0.f, 0.f);
            d1[0] = make_float4(a1[0],  a1[1],  a1[2],  a1[3]);
            d1[1] = make_float4(a1[4],  a1[5],  a1[6],  a1[7]);
            d1[2] = make_float4(a1[8],  a1[9],  a1[10], a1[11]);
            d1[3] = make_float4(a1[12], a1[13], a1[14], a1[15]);
            d1[4] = make_float4(a1[16], a1[17], a1[18], a1[19]);
            d1[5] = make_float4(a1[20], a1[21], 0.f, 0.f);
        }
        __syncthreads();

        // ---- GEMM2: acc2[r][s2] += sum_h FyT[h][i0r+r] * t2s[c][h][j0+s2] ----
        {
#pragma unroll 2
            for (int h4 = 0; h4 < 16; ++h4) {
#pragma unroll
                for (int k = 0; k < 4; ++k) {
                    const int h = 4 * h4 + k;
                    const float4 fy =
                        *reinterpret_cast<const float4*>(&FyT[h][i0r]);
                    const float2* tp =
                        reinterpret_cast<const float2*>(&t2s[c_loc][h][j0]);
                    const float2 q0 = tp[0], q1 = tp[1], q2 = tp[2];
                    const float fyv[4] = { fy.x, fy.y, fy.z, fy.w };
                    const float tv[6]  = { q0.x, q0.y, q1.x, q1.y, q2.x, q2.y };
#pragma unroll
                    for (int r = 0; r < 4; ++r)
#pragma unroll
                        for (int s2 = 0; s2 < 6; ++s2)
                            acc2[r][s2] += fyv[r] * tv[s2];
                }
            }
        }
    }

    // ---- store: out[n][c][tq][i'][j], rows 0..7 and 40..47 are zero-pad ----
    const size_t ob =
        (((size_t)n * 64 + (size_t)(cg * 8)) * 30 + (size_t)tq) * 1056;

    // zero the 16 pad rows for this block's 8 channels
    for (int idx = tid; idx < 8 * 16 * 22; idx += 256) {
        const int c   = idx / 352;
        const int rem = idx % 352;
        const int r   = rem / 22;
        const int j   = rem % 22;
        const int ip  = (r < 8) ? r : (r + 32);
        out[ob + (size_t)c * 31680 + (size_t)(ip * 22 + j)] = 0.f;
    }

    // main 32 rows
#pragma unroll
    for (int r = 0; r < 4; ++r) {
#pragma unroll
        for (int s2 = 0; s2 < 6; ++s2) {
            const int j = j0 + s2;
            if (j < 22) {
                out[ob + (size_t)c_loc * 31680
                       + (size_t)((8 + i0r + r) * 22 + j)] = acc2[r][s2];
            }
        }
    }
}

extern "C" void kernel_launch(void* const* d_in, const int* in_sizes, int n_in,
                              void* d_out, int out_size, void* d_ws, size_t ws_size,
                              hipStream_t stream) {
    const float* x   = (const float*)d_in[0];
    const float* dx  = (const float*)d_in[1];
    const float* dy  = (const float*)d_in[2];
    const float* ls2 = (const float*)d_in[3];
    const float* ld  = (const float*)d_in[4];
    const float* lg  = (const float*)d_in[5];
    const float* dtp = (const float*)d_in[6];
    const float* ldt = (const float*)d_in[7];
    const float* lgt = (const float*)d_in[8];
    float* out = (float*)d_out;

    dim3 grid(16 * 30 * 8), block(256);
    hipLaunchKernelGGL(gst_kernel, grid, block, 0, stream,
                       x, dx, dy, ls2, ld, lg, dtp, ldt, lgt, out);
}